// Round 7
// baseline (427.316 us; speedup 1.0000x reference)
//
#include <hip/hip_runtime.h>

constexpr int NL    = 48;
constexpr int SEQ   = 1024;
constexpr int BATCH = 512;

typedef float f2 __attribute__((ext_vector_type(2)));
typedef float f4 __attribute__((ext_vector_type(4)));

__device__ __forceinline__ f2 fma2(f2 a, f2 b, f2 c) {
    return __builtin_elementwise_fma(a, b, c);   // -> v_pk_fma_f32 (2 MACs/instr)
}
__device__ __forceinline__ f2 max2(f2 a, f2 b) {
    return __builtin_elementwise_max(a, b);      // -> v_pk_max_f32
}

// 12 uniform-address ds_read_b128: conflict-free broadcast of the 48-state
// vector from LDS into registers (static indices -> stays in VGPRs).
__device__ __forceinline__ void bcast_read(const f4* __restrict__ sv4, f4 r[12]) {
    #pragma unroll
    for (int g = 0; g < 12; ++g) r[g] = sv4[g];
}

// 24 v_pk_fma_f32 against the resident transition-column pairs Ec2[]
// (Ec2[k] = {exp(T[2k][jc]), exp(T[2k+1][jc])}), 4 accumulator chains.
__device__ __forceinline__ float dot48(const f4 r[12], const f2 Ec2[24]) {
    f2 c0 = {0.f, 0.f}, c1 = {0.f, 0.f}, c2 = {0.f, 0.f}, c3 = {0.f, 0.f};
    #pragma unroll
    for (int g = 0; g < 12; g += 2) {
        c0 = fma2(r[g].xy,     Ec2[2 * g    ], c0);
        c1 = fma2(r[g].zw,     Ec2[2 * g + 1], c1);
        c2 = fma2(r[g + 1].xy, Ec2[2 * g + 2], c2);
        c3 = fma2(r[g + 1].zw, Ec2[2 * g + 3], c3);
    }
    f2 cs = (c0 + c2) + (c1 + c3);
    return cs.x + cs.y;
}

// In-register pk-max tree over the 48 broadcast values (renorm steps only).
__device__ __forceinline__ float max48(const f4 r[12]) {
    f2 x0 = max2(max2(r[0].xy,  r[0].zw),  max2(r[1].xy,  r[1].zw));
    f2 x1 = max2(max2(r[2].xy,  r[2].zw),  max2(r[3].xy,  r[3].zw));
    f2 x2 = max2(max2(r[4].xy,  r[4].zw),  max2(r[5].xy,  r[5].zw));
    f2 x3 = max2(max2(r[6].xy,  r[6].zw),  max2(r[7].xy,  r[7].zw));
    f2 x4 = max2(max2(r[8].xy,  r[8].zw),  max2(r[9].xy,  r[9].zw));
    f2 x5 = max2(max2(r[10].xy, r[10].zw), max2(r[11].xy, r[11].zw));
    f2 y  = max2(max2(x0, x1), max2(max2(x2, x3), max2(x4, x5)));
    return fmaxf(y.x, y.y);
}

// One PAIR iteration = one forward step for BOTH sequences, in 4 pinned
// phases.  Each sequence's LDS round trip (ds_write v -> 12 ds_read_b128
// -> pk-MACs) is bridged by the PARTNER's full MAC+finalize phase, so the
// ~120-180cy DS latency is off the critical path.  sched_barrier(0) pins
// the phase order (round-2 lesson: unpinned, the compiler re-serializes
// the two chains to save registers).  Per-wave DS ops are in-order, so
// write -> read needs no barrier (relied on since round 1, absmax 0.0).
// RN_: renorm on the PRE-step broadcast values (identical numerics to all
// prior rounds: rm = rcp(max), folded into both mask paths, S += log(max)).
#define PAIR_STEP(SLOT_, RN_, PF_) do {                                       \
    f4 ra_[12];                                                               \
    bcast_read(sv4A, ra_);            /* P1: broadcast A = vA(t-1) */         \
    __builtin_amdgcn_sched_barrier(0);                                        \
    {   /* P2: B's step t on rb_ (vB(t-1), read last iteration) */            \
        float ee_ = __expf(embufB[SLOT_]);                                    \
        int   mt_ = (int)((mbB >> (SLOT_)) & 1);                              \
        float rm_ = 1.0f;                                                     \
        if (RN_) {                                                            \
            float m_ = max48(rb_);                                            \
            rm_ = __builtin_amdgcn_rcpf(m_);                                  \
            SB += __logf(m_);                                                 \
        }                                                                     \
        float acc_ = dot48(rb_, Ec2);                                         \
        vB = (mt_ ? acc_ * ee_ : vB) * rm_;                                   \
        svlB[tid] = vB;                                                       \
        if (PF_) embufB[SLOT_] = empB[(8 + SLOT_) * NL];                      \
    }                                                                         \
    __builtin_amdgcn_sched_barrier(0);                                        \
    bcast_read(sv4B, rb_);            /* P3: broadcast B = vB(t) */           \
    __builtin_amdgcn_sched_barrier(0);                                        \
    {   /* P4: A's step t on ra_ (vA(t-1), read in P1) */                     \
        float ee_ = __expf(embufA[SLOT_]);                                    \
        int   mt_ = (int)((mbA >> (SLOT_)) & 1);                              \
        float rm_ = 1.0f;                                                     \
        if (RN_) {                                                            \
            float m_ = max48(ra_);                                            \
            rm_ = __builtin_amdgcn_rcpf(m_);                                  \
            SA += __logf(m_);                                                 \
        }                                                                     \
        float acc_ = dot48(ra_, Ec2);                                         \
        vA = (mt_ ? acc_ * ee_ : vA) * rm_;                                   \
        svlA[tid] = vA;                                                       \
        if (PF_) embufA[SLOT_] = empA[(8 + SLOT_) * NL];                      \
    }                                                                         \
    __builtin_amdgcn_sched_barrier(0);                                        \
} while (0)

// Block = 192 threads, 256 blocks: wave 0 = forward recurrence for TWO
// sequences (phase-staggered), waves 1-2 = gold score (one sequence each).
// No DPP/readlane in the loop (cross-lane ops stall a solo wave ~4-6cy);
// pure 2cy VALU (pk ops) + DS pipe with the latency bridged.
__global__ __launch_bounds__(192)
__attribute__((amdgpu_waves_per_eu(1, 1)))
void crf_fused(
    const float* __restrict__ emissions, const int* __restrict__ labels,
    const int* __restrict__ mask, const float* __restrict__ trans,
    const float* __restrict__ startt, const float* __restrict__ endt,
    float* __restrict__ gold_out, float* __restrict__ fwd_out)
{
    const int pb  = blockIdx.x;       // pair index
    const int tid = threadIdx.x;
    const int bA  = 2 * pb;
    const int bB  = 2 * pb + 1;

    // broadcast buffers for wave 0 only (single-wave producer+consumer,
    // DS in-order -> no barriers; waves 1-2 never touch LDS).
    __shared__ alignas(16) float svl[2][64];

    if (tid < 64) {
        // ---------------- wave 0: forward algorithm, 2 sequences ----------
        const int  j   = tid;                  // lanes 48..63 idle mirrors
        const bool act = (j < NL);
        const int  jc  = act ? j : NL - 1;

        const float* emA = emissions + (size_t)bA * SEQ * NL;
        const float* emB = emissions + (size_t)bB * SEQ * NL;
        const int*   mkA = mask + bA * SEQ;
        const int*   mkB = mask + bB * SEQ;
        float* svlA = svl[0];
        float* svlB = svl[1];
        const f4* sv4A = reinterpret_cast<const f4*>(svlA);
        const f4* sv4B = reinterpret_cast<const f4*>(svlB);

        // E column jc as register pairs, shared by both sequences.
        f2 Ec2[24];
        #pragma unroll
        for (int k = 0; k < 24; ++k) {
            f2 e_;
            e_.x = __expf(trans[(2 * k    ) * NL + jc]);
            e_.y = __expf(trans[(2 * k + 1) * NL + jc]);
            Ec2[k] = e_;
        }

        // mask ballots: one vector load + __ballot per 8-step block per seq.
        int mvA = mkA[tid & 7];
        int mvB = mkB[tid & 7];
        unsigned long long mbA = __ballot(mvA != 0);   // bits for steps 0..7
        unsigned long long mbB = __ballot(mvB != 0);
        mvA = mkA[8 + (tid & 7)];                      // preload steps 8..15
        mvB = mkB[8 + (tid & 7)];

        // init: score0 = start + emit[0]; normalize by wave max (setup only).
        float s0A = act ? (startt[jc] + emA[jc]) : -3.0e38f;
        float s0B = act ? (startt[jc] + emB[jc]) : -3.0e38f;
        float m0A = s0A, m0B = s0B;
        #pragma unroll
        for (int o = 32; o; o >>= 1) {
            m0A = fmaxf(m0A, __shfl_xor(m0A, o));
            m0B = fmaxf(m0B, __shfl_xor(m0B, o));
        }
        float vA = act ? __expf(s0A - m0A) : 0.0f;  float SA = m0A;
        float vB = act ? __expf(s0B - m0B) : 0.0f;  float SB = m0B;
        svlA[tid] = vA;
        svlB[tid] = vB;

        // 8-deep emission prefetch rings; pointers bumped 8 rows per block
        // so in-loop accesses use compile-time immediate offsets only.
        const float* empA = emA + jc;
        const float* empB = emB + jc;
        float embufA[8], embufB[8];
        #pragma unroll
        for (int t = 1; t <= 8; ++t) {
            embufA[t & 7] = empA[t * NL];
            embufB[t & 7] = empB[t * NL];
        }

        // prologue: prime rb_ with broadcast of vB(0) (after the write above;
        // per-wave DS in-order guarantees it reads the new data).
        f4 rb_[12];
        bcast_read(sv4B, rb_);

        // peeled steps 1..7 (block 0); renorm at step 5 (v from step 4).
        PAIR_STEP(1, 0, 1); PAIR_STEP(2, 0, 1); PAIR_STEP(3, 0, 1); PAIR_STEP(4, 0, 1);
        PAIR_STEP(5, 1, 1); PAIR_STEP(6, 0, 1); PAIR_STEP(7, 0, 1);
        empA += 8 * NL; empB += 8 * NL;

        // main blocks tb = 8..1008; prefetch t+8 (max 1023, no clamp).
        // renorm at tb+0 and tb+4 -> every <=4 steps (fp32-safe growth).
        for (int tb = 8; tb <= SEQ - 16; tb += 8) {
            mbA = __ballot(mvA != 0);                 // mask bits tb..tb+7
            mbB = __ballot(mvB != 0);
            mvA = mkA[tb + 8 + (tid & 7)];            // prefetch next block
            mvB = mkB[tb + 8 + (tid & 7)];
            PAIR_STEP(0, 1, 1);
            PAIR_STEP(1, 0, 1); PAIR_STEP(2, 0, 1); PAIR_STEP(3, 0, 1);
            PAIR_STEP(4, 1, 1);
            PAIR_STEP(5, 0, 1); PAIR_STEP(6, 0, 1); PAIR_STEP(7, 0, 1);
            empA += 8 * NL; empB += 8 * NL;
        }

        // peeled last block t = 1016..1023: rings already full, no prefetch.
        mbA = __ballot(mvA != 0);
        mbB = __ballot(mvB != 0);
        PAIR_STEP(0, 1, 0);
        PAIR_STEP(1, 0, 0); PAIR_STEP(2, 0, 0); PAIR_STEP(3, 0, 0);
        PAIR_STEP(4, 1, 0);
        PAIR_STEP(5, 0, 0); PAIR_STEP(6, 0, 0); PAIR_STEP(7, 0, 0);

        // fwd = S + log(sum_j v[j] * exp(end[j])) over active lanes.
        float et = __expf(endt[jc]);
        float wA = act ? vA * et : 0.0f;
        float wB = act ? vB * et : 0.0f;
        #pragma unroll
        for (int o = 32; o; o >>= 1) {
            wA += __shfl_xor(wA, o);
            wB += __shfl_xor(wB, o);
        }
        if (j == 0) {
            fwd_out[bA] = SA + __logf(wA);
            fwd_out[bB] = SB + __logf(wB);
        }
    } else {
        // ---------------- waves 1-2: gold score (one sequence each) -------
        const int  w   = (tid >> 6) - 1;            // 0 or 1
        const int  l   = tid & 63;
        const int  seq = 2 * pb + w;
        const int* lb  = labels + seq * SEQ;
        const int* mks = mask + seq * SEQ;
        const float* ems = emissions + (size_t)seq * SEQ * NL;

        float part = 0.0f; int mcnt = 0;
        for (int t = l; t < SEQ; t += 64) {
            int lt = lb[t];
            int mt = mks[t];
            mcnt += mt;
            if (t == 0) {
                part += startt[lt] + ems[lt];
            } else {
                float e  = ems[t * NL + lt];
                float tr = trans[lt * NL + lb[t - 1]];   // gold uses T[cur][prev]
                if (mt) part += e + tr;
            }
        }
        #pragma unroll
        for (int o = 32; o; o >>= 1) {
            part += __shfl_xor(part, o);
            mcnt += __shfl_xor(mcnt, o);
        }
        if (l == 0) {
            int len = mcnt - 1;
            gold_out[seq] = part + endt[lb[len]];
        }
    }
}

__global__ __launch_bounds__(64) void crf_reduce(
    const float* __restrict__ gold, const float* __restrict__ fwd,
    float* __restrict__ out)
{
    const int l = threadIdx.x;
    float s = 0.0f;
    for (int bIdx = l; bIdx < BATCH; bIdx += 64) s += fwd[bIdx] - gold[bIdx];
    #pragma unroll
    for (int o = 32; o; o >>= 1) s += __shfl_xor(s, o);
    if (l == 0) out[0] = s * (1.0f / (float)BATCH);
}

extern "C" void kernel_launch(void* const* d_in, const int* in_sizes, int n_in,
                              void* d_out, int out_size, void* d_ws, size_t ws_size,
                              hipStream_t stream) {
    const float* emissions = (const float*)d_in[0];
    const int*   labels    = (const int*)d_in[1];
    const int*   mask      = (const int*)d_in[2];
    const float* trans     = (const float*)d_in[3];
    const float* startt    = (const float*)d_in[4];
    const float* endt      = (const float*)d_in[5];
    float*       out       = (float*)d_out;
    float*       wsf       = (float*)d_ws;   // [0..512) gold, [512..1024) fwd

    crf_fused<<<BATCH / 2, 192, 0, stream>>>(emissions, labels, mask, trans,
                                             startt, endt, wsf, wsf + BATCH);
    crf_reduce<<<1, 64, 0, stream>>>(wsf, wsf + BATCH, out);
}

// Round 10
// 343.400 us; speedup vs baseline: 1.2444x; 1.2444x over previous
//
#include <hip/hip_runtime.h>

constexpr int NL    = 48;
constexpr int SEQ   = 1024;
constexpr int BATCH = 512;

// ---------------------------------------------------------------------------
// Rotation via builtin mov_dpp (compiler-managed hazards) -- used for the
// one-time index tracking (EPREP) and the renorm max butterfly.
template<int N>
__device__ __forceinline__ float rrf(float x) {
    if constexpr (N == 0) return x;
    else return __int_as_float(
        __builtin_amdgcn_mov_dpp(__float_as_int(x), 0x120 | N, 0xF, 0xF, false));
}
template<int N>
__device__ __forceinline__ unsigned rru(unsigned x) {
    if constexpr (N == 0) return x;
    else return (unsigned)
        __builtin_amdgcn_mov_dpp((int)x, 0x120 | N, 0xF, 0xF, false);
}

// Fused rotate-and-MAC: ONE v_fmac_f32_dpp (DPP rides src0 of VOP2).
// Single-instruction asm blocks -- the exact form that PASSED in r6
// (r7/r8's batched multi-instruction blocks are the container-failure
// suspect and are abandoned).
#define FMAC_DPP(ACC_, SRC_, COEF_, N_)                                       \
    asm("v_fmac_f32_dpp %0, %1, %2 row_ror:" #N_                              \
        " row_mask:0xf bank_mask:0xf"                                         \
        : "+v"(ACC_) : "v"(SRC_), "v"(COEF_))

// Chain-starting rotate-and-MUL: v_mul_f32_dpp (no zero-init dependency).
#define MUL_DPP(DST_, SRC_, COEF_, N_)                                        \
    asm("v_mul_f32_dpp %0, %1, %2 row_ror:" #N_                               \
        " row_mask:0xf bank_mask:0xf"                                         \
        : "=v"(DST_) : "v"(SRC_), "v"(COEF_))

// 3-op full-wave spread via gfx950 permlane swaps (VALU).  Across
// (stream, rotation 0..15) every original lane's value reaches every lane
// exactly once (proven r3-r6: absmax 0.0 with zero-coeff junk slots).
__device__ __forceinline__ void spread4(unsigned x,
        unsigned &c, unsigned &d, unsigned &e, unsigned &f) {
    auto rA = __builtin_amdgcn_permlane32_swap(x, x, false, false);
    auto rc = __builtin_amdgcn_permlane16_swap(rA[0], rA[0], false, false);
    auto re = __builtin_amdgcn_permlane16_swap(rA[1], rA[1], false, false);
    c = rc[0]; d = rc[1]; e = re[0]; f = re[1];
}

// Rotation N of streams c,d,e: FMACs into three named chains.
#define RF3A(N_, x0_, x1_, x2_)                                               \
    FMAC_DPP(x0_, c_, EA[N_], N_);                                            \
    FMAC_DPP(x1_, d_, EB[N_], N_);                                            \
    FMAC_DPP(x2_, e_, EC[N_], N_);
// Rotation N of streams c,d,e: chain-starting MULs.
#define RM3(N_, x0_, x1_, x2_)                                                \
    MUL_DPP(x0_, c_, EA[N_], N_);                                             \
    MUL_DPP(x1_, d_, EB[N_], N_);                                             \
    MUL_DPP(x2_, e_, EC[N_], N_);

// One forward step: 3 permlane + s_nop + 64 rotate-MACs on TWELVE
// accumulator chains (r9 theory: r6's 6 chains gave ~12cy reuse distance,
// shorter than v_fmac_f32_dpp's result latency -> ~6cy stall per MAC =
// the entire 390cy/step gap.  12 chains double the reuse distance).
// Emission exp is PRE-COMPUTED at the 8-block boundary (eeb[]).
// RN_: renorm max over pre-step streams, 4-deep row_ror butterfly;
// rm_ = rcp(max) folded into both mask paths (exact identity);
// S += log(max).  Same MAC set as r6 -> absmax unchanged.
#define CRF_STEP(SLOT_, RN_) do {                                             \
    float ee_ = eeb[SLOT_];                                                   \
    int   mt_ = (int)((mb_cur >> (SLOT_)) & 1);                               \
    unsigned cu_, du_, eu_, fu_;                                              \
    spread4(__float_as_uint(v), cu_, du_, eu_, fu_);                          \
    /* >=2 wait states between permlane writes and first asm DPP read */     \
    asm("s_nop 1" : "+v"(cu_), "+v"(du_), "+v"(eu_));                         \
    float c_ = __uint_as_float(cu_), d_ = __uint_as_float(du_);               \
    float e_ = __uint_as_float(eu_), f_ = __uint_as_float(fu_);               \
    float rm_ = 1.0f;                                                         \
    if (RN_) {                                                                \
        float g_ = fmaxf(fmaxf(c_, d_), e_);                                  \
        g_ = fmaxf(g_, rrf<8>(g_));  g_ = fmaxf(g_, rrf<4>(g_));              \
        g_ = fmaxf(g_, rrf<2>(g_));  g_ = fmaxf(g_, rrf<1>(g_));              \
        rm_ = __builtin_amdgcn_rcpf(g_);                                      \
        S += __logf(g_);                                                      \
    }                                                                         \
    float a9_ = c_ * EA[0], a10_ = d_ * EB[0], a11_ = e_ * EC[0];             \
    float a0_, a1_, a2_, a3_, a4_, a5_, a6_, a7_, a8_;                        \
    RM3(1, a0_, a1_, a2_);  RM3(2, a3_, a4_, a5_);  RM3(3, a6_, a7_, a8_);    \
    RF3A(4,  a9_, a10_, a11_);                                                \
    RF3A(5,  a0_, a1_, a2_); RF3A(6,  a3_, a4_, a5_); RF3A(7,  a6_, a7_, a8_);\
    RF3A(8,  a9_, a10_, a11_);                                                \
    RF3A(9,  a0_, a1_, a2_); RF3A(10, a3_, a4_, a5_); RF3A(11, a6_, a7_, a8_);\
    RF3A(12, a9_, a10_, a11_);                                                \
    RF3A(13, a0_, a1_, a2_); RF3A(14, a3_, a4_, a5_); RF3A(15, a6_, a7_, a8_);\
    if (useF) {   /* wave-uniform; ground truth from index tracking */        \
        a9_ = fmaf(f_, ED[0], a9_);                                           \
        FMAC_DPP(a10_, f_, ED[1],  1);  FMAC_DPP(a11_, f_, ED[2],  2);        \
        FMAC_DPP(a0_,  f_, ED[3],  3);  FMAC_DPP(a1_,  f_, ED[4],  4);        \
        FMAC_DPP(a2_,  f_, ED[5],  5);  FMAC_DPP(a3_,  f_, ED[6],  6);        \
        FMAC_DPP(a4_,  f_, ED[7],  7);  FMAC_DPP(a5_,  f_, ED[8],  8);        \
        FMAC_DPP(a6_,  f_, ED[9],  9);  FMAC_DPP(a7_,  f_, ED[10], 10);       \
        FMAC_DPP(a8_,  f_, ED[11], 11); FMAC_DPP(a9_,  f_, ED[12], 12);       \
        FMAC_DPP(a10_, f_, ED[13], 13); FMAC_DPP(a11_, f_, ED[14], 14);       \
        FMAC_DPP(a0_,  f_, ED[15], 15);                                       \
    }                                                                         \
    float t0_ = a0_ + a1_,  t1_ = a2_ + a3_,  t2_ = a4_ + a5_;                \
    float t3_ = a6_ + a7_,  t4_ = a8_ + a9_,  t5_ = a10_ + a11_;              \
    float acc_ = ((t0_ + t1_) + (t2_ + t3_)) + (t4_ + t5_);                   \
    v = (mt_ ? acc_ * ee_ : v) * rm_;                                         \
} while (0)

// Coefficient prep: push the PER-LANE STATE ID (sigma) through the same
// spread+rotate network; pairing correct by construction for any HW
// permlane/DPP semantics (junk states >= 48 get coefficient 0).
#define EPREP(N_) do {                                                        \
    unsigned i0 = rru<N_>(ic_), i1 = rru<N_>(id_);                            \
    unsigned i2 = rru<N_>(ie_), i3 = rru<N_>(if_);                            \
    EA[N_] = (i0 < (unsigned)NL) ? __expf(trans[i0 * NL + jc]) : 0.0f;        \
    EB[N_] = (i1 < (unsigned)NL) ? __expf(trans[i1 * NL + jc]) : 0.0f;        \
    EC[N_] = (i2 < (unsigned)NL) ? __expf(trans[i2 * NL + jc]) : 0.0f;        \
    ED[N_] = (i3 < (unsigned)NL) ? __expf(trans[i3 * NL + jc]) : 0.0f;        \
} while (0)

// Block = 128: wave 0 = forward recurrence (1 sequence), wave 1 = gold.
// Wall time = 1023 x single-seq step time (r7 lesson: never co-locate two
// sequences in one wave -- SIMDs are free, the critical path is not).
__global__ __launch_bounds__(128)
__attribute__((amdgpu_waves_per_eu(1, 1)))
void crf_fused(
    const float* __restrict__ emissions, const int* __restrict__ labels,
    const int* __restrict__ mask, const float* __restrict__ trans,
    const float* __restrict__ startt, const float* __restrict__ endt,
    float* __restrict__ gold_out, float* __restrict__ fwd_out)
{
    const int b   = blockIdx.x;
    const int tid = threadIdx.x;
    const float* em = emissions + (size_t)b * SEQ * NL;
    const int*   mk = mask + b * SEQ;

    // setup-only scratch for wave 0 (single-wave producer+consumer).
    __shared__ int gflag[64];

    if (tid < 64) {
        // ---------------- wave 0: forward algorithm ----------------
        const int j = tid;

        // --- discover which source lanes feed stream f (set G) ---
        unsigned p0_, p1_, p2_, pf_;
        spread4((unsigned)j, p0_, p1_, p2_, pf_);
        gflag[j] = 0;
        gflag[pf_ & 63] = 1;
        const int inG = gflag[j];
        const unsigned long long gball = __ballot(inG != 0);
        const int gcount = __popcll(gball);
        const unsigned long long below = (j == 0) ? 0ull : ((~0ull) >> (64 - j));

        // --- sigma: junk states onto G if |G| <= 16; else identity (r6
        // measured |G| > 16 on HW -> identity + f-block). ---
        unsigned sig;
        if (gcount <= 16)
            sig = inG ? 48u + (unsigned)__popcll(gball & below)
                      : (unsigned)__popcll(~gball & below);
        else
            sig = (unsigned)j;

        const bool act = (sig < (unsigned)NL);
        const int  jc  = act ? (int)sig : NL - 1;

        unsigned ic_, id_, ie_, if_;
        spread4(sig, ic_, id_, ie_, if_);
        const bool useF = (__ballot(if_ < (unsigned)NL) != 0ull);

        float EA[16], EB[16], EC[16], ED[16];
        EPREP(0);  EPREP(1);  EPREP(2);  EPREP(3);
        EPREP(4);  EPREP(5);  EPREP(6);  EPREP(7);
        EPREP(8);  EPREP(9);  EPREP(10); EPREP(11);
        EPREP(12); EPREP(13); EPREP(14); EPREP(15);

        // mask ballots: one vector load + __ballot per 8-step block.
        int mval = mk[tid & 7];                          // steps 0..7 (bit 0 unused)
        unsigned long long mb_cur = __ballot(mval != 0);
        mval = mk[8 + (tid & 7)];                        // preload steps 8..15

        // init: score0 = start + emit[0]; normalize by wave max.
        float s0 = act ? (startt[jc] + em[jc]) : -3.0e38f;
        float m0 = s0;
        #pragma unroll
        for (int o = 32; o; o >>= 1) m0 = fmaxf(m0, __shfl_xor(m0, o));
        float v = act ? __expf(s0 - m0) : 0.0f;
        float S = m0;

        // Emission pipeline: rawA[] holds the NEXT block's raw emissions
        // (loads in flight across a whole 8-step block); eeb[] holds the
        // CURRENT block's pre-exponentiated emissions.  Per-step cost: zero.
        const float* emp = em + jc;
        float rawA[8], eeb[8];
        #pragma unroll
        for (int t = 1; t <= 7; ++t) rawA[t] = emp[t * NL];
        #pragma unroll
        for (int t = 1; t <= 7; ++t) eeb[t] = __expf(rawA[t]);
        #pragma unroll
        for (int s = 0; s < 8; ++s) rawA[s] = emp[(8 + s) * NL];

        // peeled steps 1..7 (block 0); renorm at step 5 (v from step 4).
        CRF_STEP(1, 0); CRF_STEP(2, 0); CRF_STEP(3, 0); CRF_STEP(4, 0);
        CRF_STEP(5, 1); CRF_STEP(6, 0); CRF_STEP(7, 0);
        emp += 8 * NL;

        // main blocks tb = 8..1008; prefetch block tb+8 (max t = 1023).
        // renorm at tb+0 and tb+4 -> every <=4 steps (fp32-safe growth).
        for (int tb = 8; tb <= SEQ - 16; tb += 8) {
            mb_cur = __ballot(mval != 0);                // mask bits tb..tb+7
            mval = mk[tb + 8 + (tid & 7)];               // prefetch next block
            #pragma unroll
            for (int s = 0; s < 8; ++s) eeb[s] = __expf(rawA[s]);
            #pragma unroll
            for (int s = 0; s < 8; ++s) rawA[s] = emp[(8 + s) * NL];
            CRF_STEP(0, 1);
            CRF_STEP(1, 0); CRF_STEP(2, 0); CRF_STEP(3, 0);
            CRF_STEP(4, 1);
            CRF_STEP(5, 0); CRF_STEP(6, 0); CRF_STEP(7, 0);
            emp += 8 * NL;
        }

        // peeled last block t = 1016..1023: no prefetch.
        mb_cur = __ballot(mval != 0);
        #pragma unroll
        for (int s = 0; s < 8; ++s) eeb[s] = __expf(rawA[s]);
        CRF_STEP(0, 1);
        CRF_STEP(1, 0); CRF_STEP(2, 0); CRF_STEP(3, 0);
        CRF_STEP(4, 1);
        CRF_STEP(5, 0); CRF_STEP(6, 0); CRF_STEP(7, 0);

        // fwd = S + log(sum_j v[j] * exp(end[j])) over active lanes.
        float w = act ? v * __expf(endt[jc]) : 0.0f;
        #pragma unroll
        for (int o = 32; o; o >>= 1) w += __shfl_xor(w, o);
        if (j == 0) fwd_out[b] = S + __logf(w);
    } else {
        // ---------------- wave 1: gold score ----------------
        const int l = tid - 64;
        const int* lb = labels + b * SEQ;

        float part = 0.0f; int mcnt = 0;
        for (int t = l; t < SEQ; t += 64) {
            int lt = lb[t];
            int mt = mk[t];
            mcnt += mt;
            if (t == 0) {
                part += startt[lt] + em[lt];
            } else {
                float e  = em[t * NL + lt];
                float tr = trans[lt * NL + lb[t - 1]];   // gold uses T[cur][prev]
                if (mt) part += e + tr;
            }
        }
        #pragma unroll
        for (int o = 32; o; o >>= 1) {
            part += __shfl_xor(part, o);
            mcnt += __shfl_xor(mcnt, o);
        }
        if (l == 0) {
            int len = mcnt - 1;
            gold_out[b] = part + endt[lb[len]];
        }
    }
}

__global__ __launch_bounds__(64) void crf_reduce(
    const float* __restrict__ gold, const float* __restrict__ fwd,
    float* __restrict__ out)
{
    const int l = threadIdx.x;
    float s = 0.0f;
    for (int bIdx = l; bIdx < BATCH; bIdx += 64) s += fwd[bIdx] - gold[bIdx];
    #pragma unroll
    for (int o = 32; o; o >>= 1) s += __shfl_xor(s, o);
    if (l == 0) out[0] = s * (1.0f / (float)BATCH);
}

extern "C" void kernel_launch(void* const* d_in, const int* in_sizes, int n_in,
                              void* d_out, int out_size, void* d_ws, size_t ws_size,
                              hipStream_t stream) {
    const float* emissions = (const float*)d_in[0];
    const int*   labels    = (const int*)d_in[1];
    const int*   mask      = (const int*)d_in[2];
    const float* trans     = (const float*)d_in[3];
    const float* startt    = (const float*)d_in[4];
    const float* endt      = (const float*)d_in[5];
    float*       out       = (float*)d_out;
    float*       wsf       = (float*)d_ws;   // [0..512) gold, [512..1024) fwd

    crf_fused<<<BATCH, 128, 0, stream>>>(emissions, labels, mask, trans, startt, endt,
                                         wsf, wsf + BATCH);
    crf_reduce<<<1, 64, 0, stream>>>(wsf, wsf + BATCH, out);
}